// Round 6
// baseline (68.765 us; speedup 1.0000x reference)
//
#include <hip/hip_runtime.h>
#include <math.h>

// Problem constants
#define BDIM 8
#define NDIM 4096
#define KNBR 16
#define CDIM 192
#define COUT 192
#define TWO_C 384
#define ROWS (BDIM * NDIM)   // 32768
#define BN_EPS 1e-5f

#define BM 32                 // nodes per block (32 -> 27.1 KB LDS -> 4+ blocks/CU)
#define HS 392                // h LDS row stride in bf16 elems (784 B)
#define KSTEPS 12             // 384 / 32
#define NTILES 12             // 192 / 16

typedef __attribute__((ext_vector_type(8))) short short8;
typedef __attribute__((ext_vector_type(4))) float f32x4;

__device__ __forceinline__ unsigned short f2bf(float f) {
    unsigned int u = __builtin_bit_cast(unsigned int, f);
    u += 0x7FFFu + ((u >> 16) & 1u);   // RNE
    return (unsigned short)(u >> 16);
}
__device__ __forceinline__ float gelu_exact(float v) {
    return 0.5f * v * (1.0f + erff(v * 0.70710678118654752440f));
}

// ---------------------------------------------------------------------------
// Node 1: pack W [384][192] fp32 -> fragment-ordered bf16, + zero BN stats.
// Wtp[((ks*12 + nt)*64 + lane)*8 + j] = bf16(W[ks*32 + (lane>>4)*8 + j][nt*16 + (lane&15)])
// ---------------------------------------------------------------------------
__global__ __launch_bounds__(256)
void pack_w(const float* __restrict__ W, unsigned short* __restrict__ Wtp,
            float* __restrict__ stats) {
    if (blockIdx.x == 0) {
        for (int s = threadIdx.x; s < 2 * COUT; s += 256) stats[s] = 0.0f;
    }
    int tid = blockIdx.x * 256 + threadIdx.x;   // < 12*12*64 = 9216
    if (tid >= KSTEPS * NTILES * 64) return;
    int ks = tid / (NTILES * 64);
    int r  = tid % (NTILES * 64);
    int nt = r / 64;
    int l  = r % 64;
    int k0 = ks * 32 + ((l >> 4) << 3);
    int c  = nt * 16 + (l & 15);
    short8 o;
#pragma unroll
    for (int j = 0; j < 8; ++j)
        o[j] = (short)f2bf(W[(size_t)(k0 + j) * COUT + c]);
    *(short8*)(Wtp + (size_t)tid * 8) = o;
}

// ---------------------------------------------------------------------------
// Node 2: fused gather (fp32 x) + max-rel -> bf16 h tile (LDS) -> MFMA GEMM
// -> y bf16 + per-channel BN partial stats.
// 256 threads (4 waves), 32 nodes/block, 1024 blocks -> 4 blocks/CU resident
// (LDS 27.1 KB), ~16 waves/CU for gather latency hiding.
// batch = bid & 7 -> XCD-affine gather (3.1 MB fp32 slab per XCD L2).
// ---------------------------------------------------------------------------
__global__ __launch_bounds__(256)
void mrconv_mfma(const float* __restrict__ x,            // [B][N][C] fp32
                 const unsigned short* __restrict__ Wtp, // fragment-packed bf16
                 const int*   __restrict__ edge,         // [B][N][K]
                 unsigned short* __restrict__ y,         // [ROWS][COUT] bf16
                 float* __restrict__ stats)              // [2*COUT] zeroed
{
    __shared__ unsigned short h[BM * HS];   // 25088 B
    __shared__ int eidx[BM * KNBR];         // 2048 B

    const int t     = threadIdx.x;
    const int bid   = blockIdx.x;
    const int batch = bid & 7;
    const int tile  = bid >> 3;              // 0..127
    const int row0  = tile * BM;

    const float* xbf = x + (size_t)batch * NDIM * CDIM;
    const int* eb = edge + ((size_t)batch * NDIM + row0) * KNBR;

    for (int i = t; i < BM * KNBR; i += 256) eidx[i] = eb[i];
    __syncthreads();

    // ---- gather + max-relative (fp32): 768 (chunk,node) tasks, 3 per thread
    for (int it = 0; it < 3; ++it) {
        const int idx = it * 256 + t;
        const int cc  = idx % 24;            // channel chunk: cc*8 .. cc*8+7
        const int ln  = idx / 24;            // node 0..31
        const float* xr = xbf + (size_t)(row0 + ln) * CDIM + cc * 8;
        const float4 xa  = ((const float4*)xr)[0];
        const float4 xb4 = ((const float4*)xr)[1];
        float xif[8] = {xa.x, xa.y, xa.z, xa.w, xb4.x, xb4.y, xb4.z, xb4.w};
        float agg[8];
#pragma unroll
        for (int q = 0; q < 8; ++q) agg[q] = -INFINITY;
#pragma unroll
        for (int k = 0; k < KNBR; ++k) {
            const int j = eidx[ln * KNBR + k];
            const float* pj = xbf + (size_t)j * CDIM + cc * 8;
            const float4 a = ((const float4*)pj)[0];
            const float4 b = ((const float4*)pj)[1];
            agg[0] = fmaxf(agg[0], a.x - xif[0]);
            agg[1] = fmaxf(agg[1], a.y - xif[1]);
            agg[2] = fmaxf(agg[2], a.z - xif[2]);
            agg[3] = fmaxf(agg[3], a.w - xif[3]);
            agg[4] = fmaxf(agg[4], b.x - xif[4]);
            agg[5] = fmaxf(agg[5], b.y - xif[5]);
            agg[6] = fmaxf(agg[6], b.z - xif[6]);
            agg[7] = fmaxf(agg[7], b.w - xif[7]);
        }
        short8 xi8, a8;
#pragma unroll
        for (int q = 0; q < 8; ++q) {
            xi8[q] = (short)f2bf(xif[q]);
            a8[q]  = (short)f2bf(agg[q]);
        }
        *(short8*)&h[ln * HS + cc * 8]        = xi8;   // h[:,0:192]  = x
        *(short8*)&h[ln * HS + CDIM + cc * 8] = a8;    // h[:,192:384]= agg
    }
    __syncthreads();

    // ---- MFMA GEMM: y_tile[32][192] = h[32][384] @ W[384][192] ----
    // wave w owns cols w*48 .. +47 (3 ntiles), all 32 rows (2 mtiles).
    const int wv   = t >> 6;                 // 0..3
    const int lane = t & 63;
    const int lrow = lane & 15;
    const int lk   = (lane >> 4) << 3;

    f32x4 acc[2][3];
#pragma unroll
    for (int mt = 0; mt < 2; ++mt)
#pragma unroll
        for (int nt = 0; nt < 3; ++nt)
            acc[mt][nt] = (f32x4){0.f, 0.f, 0.f, 0.f};

    for (int ks = 0; ks < KSTEPS; ++ks) {
        short8 bfr[3], afr[2];
#pragma unroll
        for (int nt = 0; nt < 3; ++nt) {
            const int ng = wv * 3 + nt;
            bfr[nt] = *(const short8*)(Wtp + (size_t)((ks * NTILES + ng) * 64 + lane) * 8);
        }
#pragma unroll
        for (int mt = 0; mt < 2; ++mt)
            afr[mt] = *(const short8*)&h[(mt * 16 + lrow) * HS + ks * 32 + lk];
#pragma unroll
        for (int mt = 0; mt < 2; ++mt)
#pragma unroll
            for (int nt = 0; nt < 3; ++nt)
                acc[mt][nt] = __builtin_amdgcn_mfma_f32_16x16x32_bf16(
                    afr[mt], bfr[nt], acc[mt][nt], 0, 0, 0);
    }

    // ---- write y (bf16) + BN partial stats ----
    const size_t growbase = (size_t)batch * NDIM + row0;
    const int rj = (lane >> 4) << 2;   // C/D: row = (lane>>4)*4 + j
#pragma unroll
    for (int mt = 0; mt < 2; ++mt) {
#pragma unroll
        for (int nt = 0; nt < 3; ++nt) {
            const int col = wv * 48 + nt * 16 + lrow;   // C/D: col = lane&15
#pragma unroll
            for (int j = 0; j < 4; ++j) {
                const size_t rr = growbase + mt * 16 + rj + j;
                y[rr * COUT + col] = f2bf(acc[mt][nt][j]);
            }
        }
    }

#pragma unroll
    for (int nt = 0; nt < 3; ++nt) {
        float s = 0.f, q = 0.f;
#pragma unroll
        for (int mt = 0; mt < 2; ++mt)
#pragma unroll
            for (int j = 0; j < 4; ++j) {
                const float v = acc[mt][nt][j];
                s += v; q += v * v;
            }
        s += __shfl_xor(s, 16); s += __shfl_xor(s, 32);
        q += __shfl_xor(q, 16); q += __shfl_xor(q, 32);
        if (lane < 16) {
            const int col = wv * 48 + nt * 16 + lane;
            atomicAdd(&stats[col], s);
            atomicAdd(&stats[COUT + col], q);
        }
    }
}

// ---------------------------------------------------------------------------
// Node 3: BN-apply + exact GELU: bf16 y -> fp32 out. 8 elems/thread.
// ---------------------------------------------------------------------------
__global__ __launch_bounds__(256)
void bn_gelu(const unsigned short* __restrict__ y,
             const float* __restrict__ stats,
             const float* __restrict__ gamma,
             const float* __restrict__ beta,
             float* __restrict__ out)
{
    __shared__ float sscale[COUT];
    __shared__ float sshift[COUT];
    const int t = threadIdx.x;
    if (t < COUT) {
        const float inv  = 1.0f / (float)ROWS;
        const float mean = stats[t] * inv;
        const float var  = stats[COUT + t] * inv - mean * mean;
        const float rstd = rsqrtf(var + BN_EPS);
        const float sc   = rstd * gamma[t];
        sscale[t] = sc;
        sshift[t] = beta[t] - mean * sc;
    }
    __syncthreads();

    const int i = blockIdx.x * 256 + t;          // grid sized exactly: 786432
    if (i >= ROWS * COUT / 8) return;
    short8 v = *(const short8*)(y + (size_t)i * 8);
    const int c0 = (i % 24) * 8;
    float4 o0, o1;
    #define BF2F(u) __builtin_bit_cast(float, (unsigned int)((unsigned short)(u)) << 16)
    o0.x = gelu_exact(fmaf(BF2F(v[0]), sscale[c0 + 0], sshift[c0 + 0]));
    o0.y = gelu_exact(fmaf(BF2F(v[1]), sscale[c0 + 1], sshift[c0 + 1]));
    o0.z = gelu_exact(fmaf(BF2F(v[2]), sscale[c0 + 2], sshift[c0 + 2]));
    o0.w = gelu_exact(fmaf(BF2F(v[3]), sscale[c0 + 3], sshift[c0 + 3]));
    o1.x = gelu_exact(fmaf(BF2F(v[4]), sscale[c0 + 4], sshift[c0 + 4]));
    o1.y = gelu_exact(fmaf(BF2F(v[5]), sscale[c0 + 5], sshift[c0 + 5]));
    o1.z = gelu_exact(fmaf(BF2F(v[6]), sscale[c0 + 6], sshift[c0 + 6]));
    o1.w = gelu_exact(fmaf(BF2F(v[7]), sscale[c0 + 7], sshift[c0 + 7]));
    #undef BF2F
    float4* po = (float4*)(out + (size_t)i * 8);
    po[0] = o0;
    po[1] = o1;
}

// ---------------------------------------------------------------------------
extern "C" void kernel_launch(void* const* d_in, const int* in_sizes, int n_in,
                              void* d_out, int out_size, void* d_ws, size_t ws_size,
                              hipStream_t stream) {
    const float* x     = (const float*)d_in[0];
    const float* W     = (const float*)d_in[1];
    // d_in[2] (bias) unused: BatchNorm mean-subtraction cancels it exactly.
    const float* gamma = (const float*)d_in[3];
    const float* beta  = (const float*)d_in[4];
    const int*   edge  = (const int*)d_in[5];
    float* out = (float*)d_out;

    unsigned short* Wtp  = (unsigned short*)d_ws;                    // 147456 B
    float* stats = (float*)(Wtp + (size_t)KSTEPS * NTILES * 64 * 8); // 1536 B
    unsigned short* y16  = (unsigned short*)(stats + 2 * COUT);      // 12.58 MB

    pack_w<<<dim3(36), dim3(256), 0, stream>>>(W, Wtp, stats);
    mrconv_mfma<<<dim3(ROWS / BM), dim3(256), 0, stream>>>(x, Wtp, edge, y16, stats);
    bn_gelu<<<dim3(ROWS * COUT / 8 / 256), dim3(256), 0, stream>>>(y16, stats, gamma, beta, out);
}

// Round 7
// 49.749 us; speedup vs baseline: 1.3822x; 1.3822x over previous
//
#include <hip/hip_runtime.h>
#include <math.h>

// Problem constants
#define BDIM 8
#define NDIM 4096
#define KNBR 16
#define CDIM 192
#define COUT 192
#define TWO_C 384
#define ROWS (BDIM * NDIM)   // 32768
#define BN_EPS 1e-5f

#define BM 64                 // nodes per block
#define HS 392                // h LDS row stride in bf16 elems (784 B)
#define KSTEPS 12             // 384 / 32
#define NTILES 12             // 192 / 16

typedef __attribute__((ext_vector_type(8))) short short8;
typedef __attribute__((ext_vector_type(4))) float f32x4;

__device__ __forceinline__ float bf2f(unsigned short u) {
    unsigned int x = ((unsigned int)u) << 16;
    return __builtin_bit_cast(float, x);
}
__device__ __forceinline__ unsigned short f2bf(float f) {
    unsigned int u = __builtin_bit_cast(unsigned int, f);
    u += 0x7FFFu + ((u >> 16) & 1u);   // RNE
    return (unsigned short)(u >> 16);
}
__device__ __forceinline__ float gelu_exact(float v) {
    return 0.5f * v * (1.0f + erff(v * 0.70710678118654752440f));
}

// ---------------------------------------------------------------------------
// Node 1 "prep": ONE kernel doing three independent jobs:
//   blocks 0..35   : pack W [384][192] fp32 -> fragment-ordered bf16
//   block  36      : zero BN stats
//   blocks 37..3108: x fp32 -> bf16 mirror (halves gather L2 bytes)
// ---------------------------------------------------------------------------
#define CVT_BLK0 37
__global__ __launch_bounds__(256)
void prep(const float* __restrict__ x, const float* __restrict__ W,
          unsigned short* __restrict__ xb, unsigned short* __restrict__ Wtp,
          float* __restrict__ stats) {
    const int bid = blockIdx.x;
    const int t   = threadIdx.x;
    if (bid < 36) {
        // pack W: Wtp[((ks*12+nt)*64+l)*8+j] = bf16(W[ks*32+(l>>4)*8+j][nt*16+(l&15)])
        const int tid = bid * 256 + t;      // < 9216 exactly
        const int ks = tid / (NTILES * 64);
        const int r  = tid % (NTILES * 64);
        const int nt = r / 64;
        const int l  = r % 64;
        const int k0 = ks * 32 + ((l >> 4) << 3);
        const int c  = nt * 16 + (l & 15);
        short8 o;
#pragma unroll
        for (int j = 0; j < 8; ++j)
            o[j] = (short)f2bf(W[(size_t)(k0 + j) * COUT + c]);
        *(short8*)(Wtp + (size_t)tid * 8) = o;
        return;
    }
    if (bid == 36) {
        for (int s = t; s < 2 * COUT; s += 256) stats[s] = 0.0f;
        return;
    }
    // cvt x: 8 floats/thread; (3109-37)*256 = 786432 threads == ROWS*CDIM/8
    const int i = (bid - CVT_BLK0) * 256 + t;
    const float4* p = (const float4*)(x + (size_t)i * 8);
    const float4 a = p[0], b = p[1];
    short8 o;
    o[0] = (short)f2bf(a.x); o[1] = (short)f2bf(a.y);
    o[2] = (short)f2bf(a.z); o[3] = (short)f2bf(a.w);
    o[4] = (short)f2bf(b.x); o[5] = (short)f2bf(b.y);
    o[6] = (short)f2bf(b.z); o[7] = (short)f2bf(b.w);
    *(short8*)(xb + (size_t)i * 8) = o;
}

// ---------------------------------------------------------------------------
// Node 2: fused gather (bf16 x) + max-rel -> bf16 h tile (LDS) -> MFMA GEMM
// -> y bf16 + per-channel BN partial stats.
// Key algebraic rewrite: max_k(x_j - x_i) == (max_k x_j) - x_i  (x_i is
// k-invariant) -> inner loop is cvt+max only, one subtract at the end.
// 256 threads (4 waves), 64 nodes/block, 512 blocks.
// batch = bid & 7 -> XCD-affine gather (1.6 MB bf16 slab per XCD L2).
// ---------------------------------------------------------------------------
__global__ __launch_bounds__(256)
void mrconv_mfma(const unsigned short* __restrict__ xb,  // [B][N][C] bf16
                 const unsigned short* __restrict__ Wtp, // fragment-packed bf16
                 const int*   __restrict__ edge,         // [B][N][K]
                 unsigned short* __restrict__ y,         // [ROWS][COUT] bf16
                 float* __restrict__ stats)              // [2*COUT] zeroed
{
    __shared__ unsigned short h[BM * HS];   // 50176 B
    __shared__ int eidx[BM * KNBR];         // 4096 B

    const int t     = threadIdx.x;
    const int bid   = blockIdx.x;
    const int batch = bid & 7;
    const int tile  = bid >> 3;              // 0..63
    const int row0  = tile * BM;

    const unsigned short* xbb = xb + (size_t)batch * NDIM * CDIM;
    const int* eb = edge + ((size_t)batch * NDIM + row0) * KNBR;

    for (int i = t; i < BM * KNBR; i += 256) eidx[i] = eb[i];
    __syncthreads();

    // ---- gather + max: 1536 (chunk,node) tasks, 6 per thread ----
    for (int it = 0; it < 6; ++it) {
        const int idx = it * 256 + t;
        const int cc  = idx % 24;            // channel chunk: cc*8 .. cc*8+7
        const int ln  = idx / 24;            // node 0..63
        const short8 xi8 = *(const short8*)(xbb + (size_t)(row0 + ln) * CDIM + cc * 8);
        float mx[8];
#pragma unroll
        for (int q = 0; q < 8; ++q) mx[q] = -INFINITY;
#pragma unroll
        for (int k = 0; k < KNBR; ++k) {
            const int j = eidx[ln * KNBR + k];
            const short8 xj8 = *(const short8*)(xbb + (size_t)j * CDIM + cc * 8);
#pragma unroll
            for (int q = 0; q < 8; ++q)
                mx[q] = fmaxf(mx[q], bf2f((unsigned short)xj8[q]));
        }
        short8 a8;
#pragma unroll
        for (int q = 0; q < 8; ++q)
            a8[q] = (short)f2bf(mx[q] - bf2f((unsigned short)xi8[q]));
        *(short8*)&h[ln * HS + cc * 8]        = xi8;   // h[:,0:192]  = x
        *(short8*)&h[ln * HS + CDIM + cc * 8] = a8;    // h[:,192:384]= agg
    }
    __syncthreads();

    // ---- MFMA GEMM: y_tile[64][192] = h[64][384] @ W[384][192] ----
    // wave wv owns cols wv*48 .. +47 (3 ntiles), all 64 rows (4 mtiles).
    const int wv   = t >> 6;                 // 0..3
    const int lane = t & 63;
    const int lrow = lane & 15;
    const int lk   = (lane >> 4) << 3;

    f32x4 acc[4][3];
#pragma unroll
    for (int mt = 0; mt < 4; ++mt)
#pragma unroll
        for (int nt = 0; nt < 3; ++nt)
            acc[mt][nt] = (f32x4){0.f, 0.f, 0.f, 0.f};

    for (int ks = 0; ks < KSTEPS; ++ks) {
        short8 bfr[3], afr[4];
#pragma unroll
        for (int nt = 0; nt < 3; ++nt) {
            const int ng = wv * 3 + nt;
            bfr[nt] = *(const short8*)(Wtp + (size_t)((ks * NTILES + ng) * 64 + lane) * 8);
        }
#pragma unroll
        for (int mt = 0; mt < 4; ++mt)
            afr[mt] = *(const short8*)&h[(mt * 16 + lrow) * HS + ks * 32 + lk];
#pragma unroll
        for (int mt = 0; mt < 4; ++mt)
#pragma unroll
            for (int nt = 0; nt < 3; ++nt)
                acc[mt][nt] = __builtin_amdgcn_mfma_f32_16x16x32_bf16(
                    afr[mt], bfr[nt], acc[mt][nt], 0, 0, 0);
    }

    // ---- write y (bf16) + BN partial stats ----
    const size_t growbase = (size_t)batch * NDIM + row0;
    const int rj = (lane >> 4) << 2;   // C/D: row = (lane>>4)*4 + j
#pragma unroll
    for (int mt = 0; mt < 4; ++mt) {
#pragma unroll
        for (int nt = 0; nt < 3; ++nt) {
            const int col = wv * 48 + nt * 16 + lrow;   // C/D: col = lane&15
#pragma unroll
            for (int j = 0; j < 4; ++j) {
                const size_t rr = growbase + mt * 16 + rj + j;
                y[rr * COUT + col] = f2bf(acc[mt][nt][j]);
            }
        }
    }

#pragma unroll
    for (int nt = 0; nt < 3; ++nt) {
        float s = 0.f, q = 0.f;
#pragma unroll
        for (int mt = 0; mt < 4; ++mt)
#pragma unroll
            for (int j = 0; j < 4; ++j) {
                const float v = acc[mt][nt][j];
                s += v; q += v * v;
            }
        s += __shfl_xor(s, 16); s += __shfl_xor(s, 32);
        q += __shfl_xor(q, 16); q += __shfl_xor(q, 32);
        if (lane < 16) {
            const int col = wv * 48 + nt * 16 + lane;
            atomicAdd(&stats[col], s);
            atomicAdd(&stats[COUT + col], q);
        }
    }
}

// ---------------------------------------------------------------------------
// Node 3: BN-apply + exact GELU: bf16 y -> fp32 out. 8 elems/thread.
// ---------------------------------------------------------------------------
__global__ __launch_bounds__(256)
void bn_gelu(const unsigned short* __restrict__ y,
             const float* __restrict__ stats,
             const float* __restrict__ gamma,
             const float* __restrict__ beta,
             float* __restrict__ out)
{
    __shared__ float sscale[COUT];
    __shared__ float sshift[COUT];
    const int t = threadIdx.x;
    if (t < COUT) {
        const float inv  = 1.0f / (float)ROWS;
        const float mean = stats[t] * inv;
        const float var  = stats[COUT + t] * inv - mean * mean;
        const float rstd = rsqrtf(var + BN_EPS);
        const float sc   = rstd * gamma[t];
        sscale[t] = sc;
        sshift[t] = beta[t] - mean * sc;
    }
    __syncthreads();

    const int i = blockIdx.x * 256 + t;          // grid sized exactly: 786432/256
    short8 v = *(const short8*)(y + (size_t)i * 8);
    const int c0 = (i % 24) * 8;
    float4 o0, o1;
    o0.x = gelu_exact(fmaf(bf2f((unsigned short)v[0]), sscale[c0 + 0], sshift[c0 + 0]));
    o0.y = gelu_exact(fmaf(bf2f((unsigned short)v[1]), sscale[c0 + 1], sshift[c0 + 1]));
    o0.z = gelu_exact(fmaf(bf2f((unsigned short)v[2]), sscale[c0 + 2], sshift[c0 + 2]));
    o0.w = gelu_exact(fmaf(bf2f((unsigned short)v[3]), sscale[c0 + 3], sshift[c0 + 3]));
    o1.x = gelu_exact(fmaf(bf2f((unsigned short)v[4]), sscale[c0 + 4], sshift[c0 + 4]));
    o1.y = gelu_exact(fmaf(bf2f((unsigned short)v[5]), sscale[c0 + 5], sshift[c0 + 5]));
    o1.z = gelu_exact(fmaf(bf2f((unsigned short)v[6]), sscale[c0 + 6], sshift[c0 + 6]));
    o1.w = gelu_exact(fmaf(bf2f((unsigned short)v[7]), sscale[c0 + 7], sshift[c0 + 7]));
    float4* po = (float4*)(out + (size_t)i * 8);
    po[0] = o0;
    po[1] = o1;
}

// ---------------------------------------------------------------------------
extern "C" void kernel_launch(void* const* d_in, const int* in_sizes, int n_in,
                              void* d_out, int out_size, void* d_ws, size_t ws_size,
                              hipStream_t stream) {
    const float* x     = (const float*)d_in[0];
    const float* W     = (const float*)d_in[1];
    // d_in[2] (bias) unused: BatchNorm mean-subtraction cancels it exactly.
    const float* gamma = (const float*)d_in[3];
    const float* beta  = (const float*)d_in[4];
    const int*   edge  = (const int*)d_in[5];
    float* out = (float*)d_out;

    unsigned short* Wtp  = (unsigned short*)d_ws;                    // 147456 B
    float* stats = (float*)(Wtp + (size_t)KSTEPS * NTILES * 64 * 8); // 1536 B
    unsigned short* y16  = (unsigned short*)(stats + 2 * COUT);      // 12.58 MB
    unsigned short* xb16 = y16 + (size_t)ROWS * COUT;                // 12.58 MB

    prep<<<dim3(CVT_BLK0 + ROWS * CDIM / 8 / 256), dim3(256), 0, stream>>>(x, W, xb16, Wtp, stats);
    mrconv_mfma<<<dim3(ROWS / BM), dim3(256), 0, stream>>>(xb16, Wtp, edge, y16, stats);
    bn_gelu<<<dim3(ROWS * COUT / 8 / 256), dim3(256), 0, stream>>>(y16, stats, gamma, beta, out);
}